// Round 4
// baseline (326.681 us; speedup 1.0000x reference)
//
#include <hip/hip_runtime.h>
#include <hip/hip_bf16.h>

#define NN 100000
#define MM 32
#define NCAPS_ 8
#define HH 64
#define FAN 512  // NCAPS*H

typedef __attribute__((ext_vector_type(8))) short bf16x8;
typedef __attribute__((ext_vector_type(4))) float f32x4;

__device__ inline short f2bf(float f) {
  union { float f; unsigned u; } v; v.f = f;
  unsigned u = v.u;
  u += 0x7FFFu + ((u >> 16) & 1u);   // round-to-nearest-even
  return (short)(u >> 16);
}

__device__ inline float bf2f(unsigned short us) {
  union { unsigned u; float f; } c;
  c.u = ((unsigned)us) << 16;
  return c.f;
}

__device__ inline bf16x8 cvt8(f32x4 lo, f32x4 hi) {
  bf16x8 r;
  r[0] = f2bf(lo[0]); r[1] = f2bf(lo[1]); r[2] = f2bf(lo[2]); r[3] = f2bf(lo[3]);
  r[4] = f2bf(hi[0]); r[5] = f2bf(hi[1]); r[6] = f2bf(hi[2]); r[7] = f2bf(hi[3]);
  return r;
}

// ---------------------------------------------------------------------------
// f32 -> bf16 streaming conversion (W: 262144 elems; x: 51.2M elems)
// ---------------------------------------------------------------------------
__global__ __launch_bounds__(256) void conv_kernel(
    const float* __restrict__ src, short* __restrict__ dst) {
  const int i = (blockIdx.x * 256 + threadIdx.x) * 8;
  f32x4 lo = *(const f32x4*)(src + i);
  f32x4 hi = *(const f32x4*)(src + i + 4);
  *(bf16x8*)(dst + i) = cvt8(lo, hi);
}

// ---------------------------------------------------------------------------
// Kernel A: per-node aggregation, one wave per node, lane = dim within H=64.
// MODE 0: gather bf16 from xbf, write bf16    (fast path)
// MODE 1: gather f32  from x,   write bf16    (mid path)
// MODE 2: gather f32  from x,   write f32     (no-ws fallback)
// Phase 0: one vector load of 32 (node,rel) pairs + readlane -> SGPRs.
// Phase 1: all 32 gathers issued back-to-back (32-deep MLP) + residuals.
// Phase 2: masked select + rel-switch accumulate.
// ---------------------------------------------------------------------------
template <int MODE>
__global__ __launch_bounds__(256) void agg_kernel(
    const float* __restrict__ x,
    const unsigned short* __restrict__ xbf,
    const int* __restrict__ nb_node,
    const int* __restrict__ nb_rel,
    unsigned short* __restrict__ vbf,
    float* __restrict__ vf32) {
  const int gid  = blockIdx.x * blockDim.x + threadIdx.x;
  const int node = gid >> 6;
  const int lane = threadIdx.x & 63;
  if (node >= NN) return;

  const int base = node * MM;

  // phase 0
  const int eidx = base + (lane & 31);
  const int my_nb = nb_node[eidx];
  const int my_rl = nb_rel[eidx];

  int nbs[MM], rls[MM];
  unsigned ok = 0;
#pragma unroll
  for (int e = 0; e < MM; ++e) {
    nbs[e] = __builtin_amdgcn_readlane(my_nb, e);
    rls[e] = __builtin_amdgcn_readlane(my_rl, e);
    if (nbs[e] < NN) ok |= (1u << e);
  }

  // phase 1: pure loads, no dependent ops
  unsigned short v16[MM];
  float vf[MM];
#pragma unroll
  for (int e = 0; e < MM; ++e) {
    const int nbc = (nbs[e] < NN) ? nbs[e] : node;
    const size_t a = (size_t)nbc * FAN + rls[e] * HH + lane;
    if (MODE == 0) v16[e] = xbf[a];
    else           vf[e]  = x[a];
  }
  float xr[NCAPS_];
  const size_t o = (size_t)node * FAN + lane;
#pragma unroll
  for (int r = 0; r < NCAPS_; ++r)
    xr[r] = (MODE == 0) ? bf2f(xbf[o + r * HH]) : x[o + r * HH];

  // phase 2
  float acc[NCAPS_];
#pragma unroll
  for (int r = 0; r < NCAPS_; ++r) acc[r] = 0.f;
#pragma unroll
  for (int e = 0; e < MM; ++e) {
    float raw = (MODE == 0) ? bf2f(v16[e]) : vf[e];
    float val = ((ok >> e) & 1u) ? raw : 0.f;
    switch (rls[e]) {
      case 0: acc[0] += val; break;
      case 1: acc[1] += val; break;
      case 2: acc[2] += val; break;
      case 3: acc[3] += val; break;
      case 4: acc[4] += val; break;
      case 5: acc[5] += val; break;
      case 6: acc[6] += val; break;
      case 7: acc[7] += val; break;
    }
  }

#pragma unroll
  for (int r = 0; r < NCAPS_; ++r) {
    float res = acc[r] + xr[r];
    if (MODE <= 1) vbf[o + r * HH] = (unsigned short)f2bf(res);
    else           vf32[o + r * HH] = res;
  }
}

// ---------------------------------------------------------------------------
// Kernel B: out = relu(vbf @ Wbf^T + b).  128x128 tile, BK=32, double-buffered
// global_load_lds staging, 4 waves each owning a 64x64 quadrant.
// Block mapping (XCD-grouped): b = xcd + 8*(4q + cb), rb = q*8 + xcd ->
// the 4 col-blocks of one row-panel share an XCD, 8 dispatches apart, so the
// A-panel is fetched once into that XCD's L2 and reused 3x.
// ---------------------------------------------------------------------------
#define BM 128
#define BN 128
#define BK 32
#define NRB ((NN + BM - 1) / BM)   // 782
#define NRBP 784                    // padded to multiple of 8

__global__ __launch_bounds__(256) void gemm_bf_kernel(
    const short* __restrict__ vbf,   // [NN][FAN] bf16
    const short* __restrict__ Wbf,   // [FAN][FAN] bf16 (row-major W)
    const float* __restrict__ bias,
    float* __restrict__ out) {
  __shared__ short Ab[2][BM * BK];
  __shared__ short Bb[2][BN * BK];

  const int b = blockIdx.x;
  const int xcd = b & 7;
  const int r_ = b >> 3;
  const int cb = r_ & 3;
  const int q  = r_ >> 2;
  const int rb = q * 8 + xcd;
  if (rb >= NRB) return;

  const int tid  = threadIdx.x;
  const int lane = tid & 63;
  const int wave = tid >> 6;
  const int wr = wave >> 1, wc = wave & 1;
  const int l15 = lane & 15, kg = lane >> 4;

  const int row0 = rb * BM, col0 = cb * BN;

  f32x4 acc[4][4];
#pragma unroll
  for (int rf = 0; rf < 4; ++rf)
#pragma unroll
    for (int cf = 0; cf < 4; ++cf) acc[rf][cf] = (f32x4){0.f, 0.f, 0.f, 0.f};

  auto stage = [&](int buf, int kb) {
#pragma unroll
    for (int c = 0; c < 2; ++c) {
      const int byteoff = c * 4096 + tid * 16;
      int arow = row0 + (byteoff >> 6);
      if (arow >= NN) arow = NN - 1;                    // clamp (store guarded)
      const char* asrc = (const char*)vbf + (size_t)arow * 1024 + kb * 64 + (byteoff & 63);
      char* adst = (char*)(&Ab[buf][0]) + byteoff;
      __builtin_amdgcn_global_load_lds(
          (const __attribute__((address_space(1))) void*)asrc,
          (__attribute__((address_space(3))) void*)adst, 16, 0, 0);
      const int bcol = col0 + (byteoff >> 6);
      const char* bsrc = (const char*)Wbf + (size_t)bcol * 1024 + kb * 64 + (byteoff & 63);
      char* bdst = (char*)(&Bb[buf][0]) + byteoff;
      __builtin_amdgcn_global_load_lds(
          (const __attribute__((address_space(1))) void*)bsrc,
          (__attribute__((address_space(3))) void*)bdst, 16, 0, 0);
    }
  };

  stage(0, 0);
  __syncthreads();

  int buf = 0;
  for (int kb = 0; kb < FAN / BK; ++kb) {
    if (kb + 1 < FAN / BK) stage(buf ^ 1, kb + 1);

    bf16x8 af[4], bfr[4];
#pragma unroll
    for (int rf = 0; rf < 4; ++rf)
      af[rf] = *(const bf16x8*)(&Ab[buf][(wr * 64 + rf * 16 + l15) * BK + kg * 8]);
#pragma unroll
    for (int cf = 0; cf < 4; ++cf)
      bfr[cf] = *(const bf16x8*)(&Bb[buf][(wc * 64 + cf * 16 + l15) * BK + kg * 8]);

#pragma unroll
    for (int rf = 0; rf < 4; ++rf)
#pragma unroll
      for (int cf = 0; cf < 4; ++cf)
        acc[rf][cf] = __builtin_amdgcn_mfma_f32_16x16x32_bf16(
            af[rf], bfr[cf], acc[rf][cf], 0, 0, 0);

    __syncthreads();
    buf ^= 1;
  }

  // epilogue: bias + relu + store.  D: col=l15, row=kg*4+r within frag.
#pragma unroll
  for (int cf = 0; cf < 4; ++cf) {
    const int col = col0 + wc * 64 + cf * 16 + l15;
    const float bb = bias[col];
#pragma unroll
    for (int rf = 0; rf < 4; ++rf) {
#pragma unroll
      for (int r = 0; r < 4; ++r) {
        const int row = row0 + wr * 64 + rf * 16 + kg * 4 + r;
        if (row < NN) {
          float val = acc[rf][cf][r] + bb;
          out[(size_t)row * FAN + col] = val > 0.f ? val : 0.f;
        }
      }
    }
  }
}

// ---------------------------------------------------------------------------
// Fallback GEMM (f32 inputs, in-loop conversion) if ws too small.
// ---------------------------------------------------------------------------
__global__ __launch_bounds__(256) void gemm_f32_kernel(
    const float* vin, const float* __restrict__ W,
    const float* __restrict__ bias, float* out) {
  const int lane = threadIdx.x & 63;
  const int wave = threadIdx.x >> 6;
  const int row0 = blockIdx.x * 64;
  const int col0 = wave * 128;
  const int l15  = lane & 15;
  const int kg   = lane >> 4;

  f32x4 acc[4][8];
#pragma unroll
  for (int rf = 0; rf < 4; ++rf)
#pragma unroll
    for (int c = 0; c < 8; ++c) acc[rf][c] = (f32x4){0.f, 0.f, 0.f, 0.f};

  for (int kb = 0; kb < FAN / 32; ++kb) {
    const int k0 = kb * 32 + kg * 8;
    bf16x8 afrag[4];
#pragma unroll
    for (int rf = 0; rf < 4; ++rf) {
      int row = row0 + rf * 16 + l15;
      if (row >= NN) row = NN - 1;
      const float* p = vin + (size_t)row * FAN + k0;
      afrag[rf] = cvt8(*(const f32x4*)p, *(const f32x4*)(p + 4));
    }
#pragma unroll
    for (int c = 0; c < 8; ++c) {
      const int col = col0 + c * 16 + l15;
      const float* q = W + (size_t)col * FAN + k0;
      bf16x8 bfrag = cvt8(*(const f32x4*)q, *(const f32x4*)(q + 4));
#pragma unroll
      for (int rf = 0; rf < 4; ++rf)
        acc[rf][c] = __builtin_amdgcn_mfma_f32_16x16x32_bf16(
            afrag[rf], bfrag, acc[rf][c], 0, 0, 0);
    }
  }

#pragma unroll
  for (int c = 0; c < 8; ++c) {
    const int col = col0 + c * 16 + l15;
    const float bb = bias[col];
#pragma unroll
    for (int rf = 0; rf < 4; ++rf)
#pragma unroll
      for (int r = 0; r < 4; ++r) {
        const int row = row0 + rf * 16 + kg * 4 + r;
        if (row < NN) {
          float val = acc[rf][c][r] + bb;
          out[(size_t)row * FAN + col] = val > 0.f ? val : 0.f;
        }
      }
  }
}

extern "C" void kernel_launch(void* const* d_in, const int* in_sizes, int n_in,
                              void* d_out, int out_size, void* d_ws, size_t ws_size,
                              hipStream_t stream) {
  const float* x  = (const float*)d_in[0];
  const float* W  = (const float*)d_in[1];
  const float* b  = (const float*)d_in[2];
  const int*   nn = (const int*)d_in[3];
  const int*   nr = (const int*)d_in[4];
  float* out = (float*)d_out;

  const size_t wbf_bytes = (size_t)FAN * FAN * sizeof(short);        // 512 KB
  const size_t vbf_bytes = (size_t)NN * FAN * sizeof(short);         // 102.4 MB
  const size_t xbf_bytes = (size_t)NN * FAN * sizeof(short);         // 102.4 MB

  short* Wbf = (short*)d_ws;
  short* vbf = (short*)((char*)d_ws + wbf_bytes);
  short* xbf = (short*)((char*)d_ws + wbf_bytes + vbf_bytes);

  if (ws_size >= wbf_bytes + vbf_bytes + xbf_bytes) {
    // full fast path: bf16 gathers
    conv_kernel<<<FAN * FAN / (256 * 8), 256, 0, stream>>>(W, Wbf);
    conv_kernel<<<NN * FAN / (256 * 8), 256, 0, stream>>>(x, xbf);
    agg_kernel<0><<<(NN * 64) / 256, 256, 0, stream>>>(
        x, (const unsigned short*)xbf, nn, nr, (unsigned short*)vbf, nullptr);
    gemm_bf_kernel<<<NRBP * 4, 256, 0, stream>>>(vbf, Wbf, b, out);
  } else if (ws_size >= wbf_bytes + vbf_bytes) {
    // mid path: f32 gathers, bf16 GEMM
    conv_kernel<<<FAN * FAN / (256 * 8), 256, 0, stream>>>(W, Wbf);
    agg_kernel<1><<<(NN * 64) / 256, 256, 0, stream>>>(
        x, nullptr, nn, nr, (unsigned short*)vbf, nullptr);
    gemm_bf_kernel<<<NRBP * 4, 256, 0, stream>>>(vbf, Wbf, b, out);
  } else {
    // fallback: everything f32 via d_out
    agg_kernel<2><<<(NN * 64) / 256, 256, 0, stream>>>(
        x, nullptr, nn, nr, nullptr, out);
    gemm_f32_kernel<<<(NN + 63) / 64, 256, 0, stream>>>(out, W, b, out);
  }
}